// Round 18
// baseline (140.544 us; speedup 1.0000x reference)
//
#include <hip/hip_runtime.h>
#include <hip/hip_fp16.h>

#define N_NODES 50000
#define EMB 128
#define HID 64
#define NR 16
#define NC 16
#define NE 800000
#define J1 (NR*HID + HID)   /* 1088 = 17*64 */
#define J2 (NR*NC + NC)     /* 272  = 17*16 */
#define CAP 64              /* bucket capacity per dst */
#define NTILE 196           /* dst tiles of 256 nodes (50176 padded) */
#define SEGCAP 4500         /* edges per tile segment */
#define EPB 8192            /* edges per binA block */
#define NBA 98              /* binA blocks */
#define CAST_BLK 6250
#define BB_BLK 613
#define PAD 224             /* binB range padded to 8-aligned start for swizzle */
#define NWG1 3519           /* gemm blocks: 391 row x 9 col */
#define FBLK 391            /* fused agg1+gemm2 blocks (128 nodes each) */

typedef _Float16 f16;
typedef __attribute__((ext_vector_type(8))) _Float16 f16x8;
typedef __attribute__((ext_vector_type(4))) _Float16 f16x4;
typedef __attribute__((ext_vector_type(4))) float f32x4;

// ---- pre-pass 1: [binA (98) | cast emb->f16 (6250) | build Bt1/Bt2 (613)] --
__global__ __launch_bounds__(256)
void k_pre1(const float* __restrict__ emb, const float* __restrict__ W1,
            const float* __restrict__ root1, const float* __restrict__ W2,
            const float* __restrict__ root2, const int* __restrict__ ei,
            const int* __restrict__ et, f16* __restrict__ embh,
            f16* __restrict__ Bt1, f16* __restrict__ Bt2,
            int* __restrict__ tcnt, unsigned* __restrict__ seg) {
    __shared__ unsigned rec[EPB];           // 32 KB
    __shared__ unsigned char tl[EPB];       // 8 KB
    __shared__ int hist[256], gbase[256];
    int bx = blockIdx.x, tid = threadIdx.x;
    if (bx < NBA) {                         // ---- binA ----
        hist[tid] = 0;
        __syncthreads();
        int e0 = bx * EPB;
#pragma unroll
        for (int k = 0; k < EPB / 256; k++) {
            int i = k * 256 + tid, e = e0 + i;
            unsigned t255 = 255, r = 0;
            if (e < NE) {
                int s = ei[e], d = ei[NE + e], t = et[e];
                t255 = (unsigned)(d >> 8);
                r = (unsigned)s | ((unsigned)t << 16) | ((unsigned)(d & 255) << 20);
                atomicAdd(&hist[t255], 1);
            }
            rec[i] = r; tl[i] = (unsigned char)t255;
        }
        __syncthreads();
        gbase[tid] = (hist[tid] > 0) ? atomicAdd(&tcnt[tid], hist[tid]) : 0;
        hist[tid] = 0;                      // reuse as local cursor
        __syncthreads();
#pragma unroll
        for (int k = 0; k < EPB / 256; k++) {
            int i = k * 256 + tid;
            unsigned char t = tl[i];
            if (t != 255) {
                int pos = atomicAdd(&hist[t], 1) + gbase[t];
                if (pos < SEGCAP) seg[(size_t)t * SEGCAP + pos] = rec[i];
            }
        }
    } else if (bx < NBA + CAST_BLK) {       // ---- cast ----
        int i = (bx - NBA) * 256 + tid;
        if (i < N_NODES * EMB / 4) {
            float4 v = reinterpret_cast<const float4*>(emb)[i];
            f16x4 r = {(f16)v.x, (f16)v.y, (f16)v.z, (f16)v.w};
            reinterpret_cast<f16x4*>(embh)[i] = r;
        }
    } else {                                // ---- build B ----
        int idx = (bx - NBA - CAST_BLK) * 256 + tid;
        const int total1 = J1 * EMB;   // 139264
        const int total2 = J2 * HID;   // 17408
        if (idx < total1) {
            int j = idx / EMB, i = idx % EMB;
            float v = (j < NR*HID) ? W1[((size_t)(j >> 6) * EMB + i) * HID + (j & 63)]
                                   : root1[i * HID + (j - NR*HID)];
            Bt1[idx] = (f16)v;
        } else if (idx < total1 + total2) {
            int t = idx - total1;
            int j = t / HID, i = t % HID;
            float v = (j < NR*NC) ? W2[((size_t)(j >> 4) * HID + i) * NC + (j & 15)]
                                  : root2[i * NC + (j - NR*NC)];
            Bt2[t] = (f16)v;
        }
    }
}

// ---- main: [binB (196) | GEMM1 f16-A, bijective XCD swizzle (3519)] --------
__global__ __launch_bounds__(512)
void k_main(const f16* __restrict__ A, const f16* __restrict__ Bt,
            f16* __restrict__ C, const int* __restrict__ tcnt,
            const unsigned* __restrict__ seg, int* __restrict__ cur,
            unsigned* __restrict__ packed, unsigned long long* __restrict__ cnts) {
    constexpr int K = EMB, KP = K + 8;
    __shared__ __align__(16) char smem[128 * KP * 2 * 2];   // 69,632 B union
    int wg = blockIdx.x, tid = threadIdx.x;

    if (wg < NTILE) {                       // ================ binB ========
        int* bcnt = (int*)smem;                        // 1 KB
        unsigned* bkt = (unsigned*)(smem + 1024);      // 64 KB
        for (int i = tid; i < 256; i += 512) bcnt[i] = 0;
        __syncthreads();
        int m = tcnt[wg]; if (m > SEGCAP) m = SEGCAP;
        for (int i = tid; i < m; i += 512) {
            unsigned r = seg[(size_t)wg * SEGCAP + i];
            int dl = (r >> 20) & 255;
            int pos = atomicAdd(&bcnt[dl], 1);
            if (pos < CAP) bkt[dl * CAP + pos] = (r & 0xFFFFu) * 17u + ((r >> 16) & 15u);
        }
        __syncthreads();
        const uint4* s4 = (const uint4*)bkt;
        uint4* d4 = (uint4*)(packed + (size_t)wg * 256 * CAP);
        for (int i = tid; i < 256 * CAP / 4; i += 512) d4[i] = s4[i];
        if (tid < 256) {
            int deg = bcnt[tid]; if (deg > CAP) deg = CAP;
            unsigned long long cc = 0;
            for (int i = 0; i < deg; i++) {
                unsigned t = bkt[tid * CAP + i] % 17u;   // 0..15 for stored entries
                cc += 1ull << (4 * t);
            }
            cnts[wg * 256 + tid] = cc;
            cur[wg * 256 + tid] = bcnt[tid];
        }
        return;
    }
    if (wg < PAD) return;                   // 28 idle pad blocks
    // ================ gemm path ================
    f16* As = (f16*)smem;
    f16* Bs = As + 128 * KP;
    int g = wg - PAD;                       // PAD%8==0 -> g&7 == real XCD
    constexpr int qq = NWG1 / 8, rm = NWG1 % 8;    // 439, 7
    int x = g & 7, slot = g >> 3;
    int vg = (x < rm) ? x * (qq + 1) + slot
                      : rm * (qq + 1) + (x - rm) * qq + slot;
    int m0 = (vg / 9) * 128, n0 = (vg % 9) * 128;

    constexpr int V = K / 8;
    for (int idx = tid; idx < 128 * V; idx += 512) {
        int rr = idx / V, c = idx % V;
        f16x8 va = {}, vb = {};
        if (m0 + rr < N_NODES) va = *reinterpret_cast<const f16x8*>(A + (size_t)(m0 + rr) * K + c * 8);
        if (n0 + rr < J1)      vb = *reinterpret_cast<const f16x8*>(Bt + (size_t)(n0 + rr) * K + c * 8);
        *reinterpret_cast<f16x8*>(&As[rr * KP + c * 8]) = va;
        *reinterpret_cast<f16x8*>(&Bs[rr * KP + c * 8]) = vb;
    }
    __syncthreads();

    int w = tid >> 6, lane = tid & 63;
    int wr = (w >> 2) * 64, wc = (w & 3) * 32;
    int lr = lane & 15, lk = (lane >> 4) * 8;

    f32x4 acc[4][2];
#pragma unroll
    for (int mm = 0; mm < 4; mm++)
#pragma unroll
        for (int nn = 0; nn < 2; nn++) acc[mm][nn] = (f32x4){0.f, 0.f, 0.f, 0.f};

#pragma unroll
    for (int k0 = 0; k0 < K; k0 += 32) {
        f16x8 a[4], b[2];
#pragma unroll
        for (int mm = 0; mm < 4; mm++)
            a[mm] = *reinterpret_cast<const f16x8*>(&As[(wr + mm*16 + lr) * KP + k0 + lk]);
#pragma unroll
        for (int nn = 0; nn < 2; nn++)
            b[nn] = *reinterpret_cast<const f16x8*>(&Bs[(wc + nn*16 + lr) * KP + k0 + lk]);
#pragma unroll
        for (int mm = 0; mm < 4; mm++)
#pragma unroll
            for (int nn = 0; nn < 2; nn++)
                acc[mm][nn] = __builtin_amdgcn_mfma_f32_16x16x32_f16(a[mm], b[nn], acc[mm][nn], 0, 0, 0);
    }

    // ---- epilogue: LDS transpose (alias As/Bs) -> vectorized f16x8 stores --
    __syncthreads();                        // all frag reads drained
    f16* Cs = (f16*)smem;                   // 128 x 136 f16 = 34,816 B
    int gq = lane >> 4;
#pragma unroll
    for (int mm = 0; mm < 4; mm++)
#pragma unroll
        for (int nn = 0; nn < 2; nn++)
#pragma unroll
            for (int q = 0; q < 4; q++)
                Cs[(wr + mm*16 + gq*4 + q) * 136 + wc + nn*16 + lr] = (f16)acc[mm][nn][q];
    __syncthreads();
#pragma unroll
    for (int it = 0; it < 4; it++) {
        int idx = it * 512 + tid;
        int row = idx >> 4, cg = idx & 15;
        int grow = m0 + row, gcol = n0 + cg * 8;
        if (grow < N_NODES && gcol < J1)
            *reinterpret_cast<f16x8*>(C + (size_t)grow * J1 + gcol) =
                *reinterpret_cast<const f16x8*>(&Cs[row * 136 + cg * 8]);
    }
}

// ---- FUSED agg1 + relu + GEMM2: block = 128 nodes --------------------------
// Phase 1: 8 waves aggregate (wave/node, 16 nodes each) -> LDS Xs[128][72].
// Phase 2: wave wv computes rows [wv*16,+16) x all 272 cols vs LDS Bs[272][72].
// Requires Y2 NOT aliasing Y1 (Y1 still gathered while Y2 written).
__global__ __launch_bounds__(512)
void k_fuse(const int* __restrict__ cur, const unsigned* __restrict__ packed,
            const unsigned long long* __restrict__ cnts,
            const f16* __restrict__ Y1, const float* __restrict__ b1,
            const f16* __restrict__ Bt2, f16* __restrict__ Y2) {
    __shared__ f16 Xs[128][72];       // 18,432 B (stride 144B -> 2-way banks)
    __shared__ f16 Bs[272 * 72];      // 39,168 B
    int b = blockIdx.x, tid = threadIdx.x;
    int wv = tid >> 6, lane = tid & 63;
    int c4 = lane & 15, grp = lane >> 4;

    for (int i = tid; i < 272 * 8; i += 512) {     // stage Bt2 (padded rows)
        int r = i >> 3, c = i & 7;
        *reinterpret_cast<f16x8*>(&Bs[r * 72 + c * 8]) =
            *reinterpret_cast<const f16x8*>(Bt2 + r * 64 + c * 8);
    }

    float4 bb = *reinterpret_cast<const float4*>(b1 + c4 * 4);
    const f16* Yb = Y1 + c4 * 4;

    for (int it = 0; it < 16; ++it) {              // 16 nodes per wave
        int ln = it * 8 + wv;
        int n = b * 128 + ln;
        if (n < N_NODES) {
            int deg = cur[n]; if (deg > CAP) deg = CAP;
            unsigned long long cc = cnts[n];
            unsigned my = packed[(size_t)n * CAP + lane];
            unsigned tp = (my % 17u) & 15u;
            int myc = (int)((cc >> (4 * tp)) & 15ull);
            float w_my = 1.0f / fmaxf((float)myc, 1.0f);
            float a0 = 0.f, a1 = 0.f, a2 = 0.f, a3 = 0.f;
            for (int i = 0; i < deg; i += 8) {     // wave-uniform bound
                int idx0 = i + grp, idx1 = i + 4 + grp;   // <= 63
                unsigned e0 = __shfl(my, idx0), e1 = __shfl(my, idx1);
                float w0 = __shfl(w_my, idx0), w1 = __shfl(w_my, idx1);
                bool p0 = idx0 < deg, p1 = idx1 < deg;
                f16x4 v0 = {}, v1 = {};
                if (p0) v0 = *reinterpret_cast<const f16x4*>(Yb + ((size_t)e0 << 6));
                if (p1) v1 = *reinterpret_cast<const f16x4*>(Yb + ((size_t)e1 << 6));
                if (p0) { a0 += w0 * (float)v0[0]; a1 += w0 * (float)v0[1];
                          a2 += w0 * (float)v0[2]; a3 += w0 * (float)v0[3]; }
                if (p1) { a0 += w1 * (float)v1[0]; a1 += w1 * (float)v1[1];
                          a2 += w1 * (float)v1[2]; a3 += w1 * (float)v1[3]; }
            }
            a0 += __shfl_xor(a0, 16); a0 += __shfl_xor(a0, 32);
            a1 += __shfl_xor(a1, 16); a1 += __shfl_xor(a1, 32);
            a2 += __shfl_xor(a2, 16); a2 += __shfl_xor(a2, 32);
            a3 += __shfl_xor(a3, 16); a3 += __shfl_xor(a3, 32);
            if (grp == 0) {
                f16x4 rt = *reinterpret_cast<const f16x4*>(Y1 + ((size_t)n * 17 + 16) * 64 + c4 * 4);
                f16x4 o = {(f16)fmaxf(a0 + (float)rt[0] + bb.x, 0.f),
                           (f16)fmaxf(a1 + (float)rt[1] + bb.y, 0.f),
                           (f16)fmaxf(a2 + (float)rt[2] + bb.z, 0.f),
                           (f16)fmaxf(a3 + (float)rt[3] + bb.w, 0.f)};
                *reinterpret_cast<f16x4*>(&Xs[ln][c4 * 4]) = o;
            }
        } else if (grp == 0) {
            *reinterpret_cast<f16x4*>(&Xs[ln][c4 * 4]) = (f16x4){};
        }
    }
    __syncthreads();

    // ---- GEMM: 16 rows/wave x 272 cols, K=64 ----
    int arow = wv * 16 + c4;
    f16x8 A0 = *reinterpret_cast<const f16x8*>(&Xs[arow][grp * 8]);
    f16x8 A1 = *reinterpret_cast<const f16x8*>(&Xs[arow][32 + grp * 8]);
    f32x4 acc[17];
#pragma unroll
    for (int cf = 0; cf < 17; cf++) acc[cf] = (f32x4){0.f, 0.f, 0.f, 0.f};
#pragma unroll
    for (int cf = 0; cf < 17; cf++) {
        f16x8 B0 = *reinterpret_cast<const f16x8*>(&Bs[(cf * 16 + c4) * 72 + grp * 8]);
        f16x8 B1 = *reinterpret_cast<const f16x8*>(&Bs[(cf * 16 + c4) * 72 + 32 + grp * 8]);
        acc[cf] = __builtin_amdgcn_mfma_f32_16x16x32_f16(A0, B0, acc[cf], 0, 0, 0);
        acc[cf] = __builtin_amdgcn_mfma_f32_16x16x32_f16(A1, B1, acc[cf], 0, 0, 0);
    }
    int row0 = b * 128 + wv * 16 + grp * 4;
#pragma unroll
    for (int q = 0; q < 4; q++) {
        int row = row0 + q;
        if (row < N_NODES) {
            f16* Yr = Y2 + (size_t)row * J2 + c4;
#pragma unroll
            for (int cf = 0; cf < 17; cf++)
                Yr[cf * 16] = (f16)acc[cf][q];
        }
    }
}

// ---- MFMA GEMM for layer 2 (fallback path only) -----------------------------
template<int K, typename OutT>
__global__ __launch_bounds__(512)
void k_mfma(const f16* __restrict__ A, const f16* __restrict__ Bt,
            OutT* __restrict__ C, int N, int J) {
    constexpr int KP = K + 8;
    constexpr int SM = (2 * 128 * KP * 2 > 128 * 136 * 2) ? 2 * 128 * KP * 2
                                                          : 128 * 136 * 2;
    __shared__ __align__(16) char smem[SM];
    f16* As = (f16*)smem;
    f16* Bs = As + 128 * KP;
    int tid = threadIdx.x;
    int m0 = blockIdx.y * 128, n0 = blockIdx.x * 128;

    constexpr int V = K / 8;
    for (int idx = tid; idx < 128 * V; idx += 512) {
        int r = idx / V, c = idx % V;
        f16x8 va = {}, vb = {};
        if (m0 + r < N) va = *reinterpret_cast<const f16x8*>(A + (size_t)(m0 + r) * K + c * 8);
        if (n0 + r < J) vb = *reinterpret_cast<const f16x8*>(Bt + (size_t)(n0 + r) * K + c * 8);
        *reinterpret_cast<f16x8*>(&As[r * KP + c * 8]) = va;
        *reinterpret_cast<f16x8*>(&Bs[r * KP + c * 8]) = vb;
    }
    __syncthreads();

    int w = tid >> 6, lane = tid & 63;
    int wr = (w >> 2) * 64, wc = (w & 3) * 32;
    int lr = lane & 15, lk = (lane >> 4) * 8;

    f32x4 acc[4][2];
#pragma unroll
    for (int mm = 0; mm < 4; mm++)
#pragma unroll
        for (int nn = 0; nn < 2; nn++) acc[mm][nn] = (f32x4){0.f, 0.f, 0.f, 0.f};

#pragma unroll
    for (int k0 = 0; k0 < K; k0 += 32) {
        f16x8 a[4], b[2];
#pragma unroll
        for (int mm = 0; mm < 4; mm++)
            a[mm] = *reinterpret_cast<const f16x8*>(&As[(wr + mm*16 + lr) * KP + k0 + lk]);
#pragma unroll
        for (int nn = 0; nn < 2; nn++)
            b[nn] = *reinterpret_cast<const f16x8*>(&Bs[(wc + nn*16 + lr) * KP + k0 + lk]);
#pragma unroll
        for (int mm = 0; mm < 4; mm++)
#pragma unroll
            for (int nn = 0; nn < 2; nn++)
                acc[mm][nn] = __builtin_amdgcn_mfma_f32_16x16x32_f16(a[mm], b[nn], acc[mm][nn], 0, 0, 0);
    }

    __syncthreads();
    f16* Cs = (f16*)smem;                   // 128 x 136 f16
    int gq = lane >> 4;
#pragma unroll
    for (int mm = 0; mm < 4; mm++)
#pragma unroll
        for (int nn = 0; nn < 2; nn++)
#pragma unroll
            for (int q = 0; q < 4; q++)
                Cs[(wr + mm*16 + gq*4 + q) * 136 + wc + nn*16 + lr] = (f16)acc[mm][nn][q];
    __syncthreads();
#pragma unroll
    for (int it = 0; it < 4; it++) {
        int idx = it * 512 + tid;
        int row = idx >> 4, cg = idx & 15;
        int grow = m0 + row, gcol = n0 + cg * 8;
        if (grow < N && gcol < J) {
            f16x8 v = *reinterpret_cast<const f16x8*>(&Cs[row * 136 + cg * 8]);
            if constexpr (sizeof(OutT) == 2) {
                *reinterpret_cast<f16x8*>((f16*)C + (size_t)grow * J + gcol) = v;
            } else {
#pragma unroll
                for (int j = 0; j < 8; j++)
                    C[(size_t)grow * J + gcol + j] = (OutT)v[j];
            }
        }
    }
}

// ---- fused layer-1 aggregation + finalize (fallback path only) --------------
__global__ __launch_bounds__(256)
void k_agg1f(const int* __restrict__ cur, const unsigned* __restrict__ packed,
             const unsigned long long* __restrict__ cnts,
             const f16* __restrict__ Y1, const float* __restrict__ b1,
             f16* __restrict__ X1h) {
    int n = (blockIdx.x * 256 + threadIdx.x) >> 6;
    if (n >= N_NODES) return;
    int lane = threadIdx.x & 63;
    int deg = cur[n]; if (deg > CAP) deg = CAP;
    unsigned long long cc = cnts[n];
    unsigned my = packed[(size_t)n * CAP + lane];
    unsigned tp = (my % 17u) & 15u;
    int myc = (int)((cc >> (4 * tp)) & 15ull);
    float w_my = 1.0f / fmaxf((float)myc, 1.0f);
    int c4 = lane & 15, grp = lane >> 4;
    const f16* Yb = Y1 + c4 * 4;
    float a0 = 0.f, a1 = 0.f, a2 = 0.f, a3 = 0.f;
    for (int i = 0; i < deg; i += 8) {
        int idx0 = i + grp, idx1 = i + 4 + grp;
        unsigned e0 = __shfl(my, idx0), e1 = __shfl(my, idx1);
        float w0 = __shfl(w_my, idx0), w1 = __shfl(w_my, idx1);
        bool p0 = idx0 < deg, p1 = idx1 < deg;
        f16x4 v0 = {}, v1 = {};
        if (p0) v0 = *reinterpret_cast<const f16x4*>(Yb + ((size_t)e0 << 6));
        if (p1) v1 = *reinterpret_cast<const f16x4*>(Yb + ((size_t)e1 << 6));
        if (p0) { a0 += w0 * (float)v0[0]; a1 += w0 * (float)v0[1];
                  a2 += w0 * (float)v0[2]; a3 += w0 * (float)v0[3]; }
        if (p1) { a0 += w1 * (float)v1[0]; a1 += w1 * (float)v1[1];
                  a2 += w1 * (float)v1[2]; a3 += w1 * (float)v1[3]; }
    }
    a0 += __shfl_xor(a0, 16); a0 += __shfl_xor(a0, 32);
    a1 += __shfl_xor(a1, 16); a1 += __shfl_xor(a1, 32);
    a2 += __shfl_xor(a2, 16); a2 += __shfl_xor(a2, 32);
    a3 += __shfl_xor(a3, 16); a3 += __shfl_xor(a3, 32);
    if (grp == 0) {
        f16x4 rt = *reinterpret_cast<const f16x4*>(Y1 + ((size_t)n * 17 + 16) * 64 + c4 * 4);
        float4 bb = *reinterpret_cast<const float4*>(b1 + c4 * 4);
        f16x4 o = {(f16)fmaxf(a0 + (float)rt[0] + bb.x, 0.f),
                   (f16)fmaxf(a1 + (float)rt[1] + bb.y, 0.f),
                   (f16)fmaxf(a2 + (float)rt[2] + bb.z, 0.f),
                   (f16)fmaxf(a3 + (float)rt[3] + bb.w, 0.f)};
        *reinterpret_cast<f16x4*>(X1h + (size_t)n * HID + c4 * 4) = o;
    }
}

// ---- fused layer-2 aggregation + finalize ----------------------------------
__global__ __launch_bounds__(256)
void k_agg2f(const int* __restrict__ cur, const unsigned* __restrict__ packed,
             const unsigned long long* __restrict__ cnts,
             const f16* __restrict__ Y2, const float* __restrict__ b2,
             float* __restrict__ out) {
    int n = (blockIdx.x * 256 + threadIdx.x) >> 6;
    if (n >= N_NODES) return;
    int lane = threadIdx.x & 63;
    int deg = cur[n]; if (deg > CAP) deg = CAP;
    unsigned long long cc = cnts[n];
    unsigned my = packed[(size_t)n * CAP + lane];
    unsigned tp = (my % 17u) & 15u;
    int myc = (int)((cc >> (4 * tp)) & 15ull);
    float w_my = 1.0f / fmaxf((float)myc, 1.0f);
    int c4 = lane & 3, grp = lane >> 2;             // 16 groups x 4 quads
    const f16* Yb = Y2 + c4 * 4;
    float a0 = 0.f, a1 = 0.f, a2 = 0.f, a3 = 0.f;
    for (int i = 0; i < deg; i += 32) {
        int idx0 = i + grp, idx1 = i + 16 + grp;
        unsigned e0 = __shfl(my, idx0), e1 = __shfl(my, idx1);
        float w0 = __shfl(w_my, idx0), w1 = __shfl(w_my, idx1);
        bool p0 = idx0 < deg, p1 = idx1 < deg;
        f16x4 v0 = {}, v1 = {};
        if (p0) v0 = *reinterpret_cast<const f16x4*>(Yb + ((size_t)e0 << 4));
        if (p1) v1 = *reinterpret_cast<const f16x4*>(Yb + ((size_t)e1 << 4));
        if (p0) { a0 += w0 * (float)v0[0]; a1 += w0 * (float)v0[1];
                  a2 += w0 * (float)v0[2]; a3 += w0 * (float)v0[3]; }
        if (p1) { a0 += w1 * (float)v1[0]; a1 += w1 * (float)v1[1];
                  a2 += w1 * (float)v1[2]; a3 += w1 * (float)v1[3]; }
    }
#pragma unroll
    for (int sh = 4; sh <= 32; sh <<= 1) {
        a0 += __shfl_xor(a0, sh); a1 += __shfl_xor(a1, sh);
        a2 += __shfl_xor(a2, sh); a3 += __shfl_xor(a3, sh);
    }
    if (grp == 0) {                                 // lanes 0..3
        f16x4 rt = *reinterpret_cast<const f16x4*>(Y2 + (((size_t)n * 17 + 16) << 4) + c4 * 4);
        float4 bb = *reinterpret_cast<const float4*>(b2 + c4 * 4);
        float4 o;
        o.x = 1.0f / (1.0f + expf(-(a0 + (float)rt[0] + bb.x)));
        o.y = 1.0f / (1.0f + expf(-(a1 + (float)rt[1] + bb.y)));
        o.z = 1.0f / (1.0f + expf(-(a2 + (float)rt[2] + bb.z)));
        o.w = 1.0f / (1.0f + expf(-(a3 + (float)rt[3] + bb.w)));
        *reinterpret_cast<float4*>(out + (size_t)n * NC + c4 * 4) = o;
    }
}

extern "C" void kernel_launch(void* const* d_in, const int* in_sizes, int n_in,
                              void* d_out, int out_size, void* d_ws, size_t ws_size,
                              hipStream_t stream) {
    const float* emb   = (const float*)d_in[0];
    const float* W1    = (const float*)d_in[1];
    const float* root1 = (const float*)d_in[2];
    const float* b1    = (const float*)d_in[3];
    const float* W2    = (const float*)d_in[4];
    const float* root2 = (const float*)d_in[5];
    const float* b2    = (const float*)d_in[6];
    const int*   ei    = (const int*)d_in[7];    // [2, NE]: src then dst
    const int*   et    = (const int*)d_in[8];
    float* out = (float*)d_out;

    char* ws = (char*)d_ws;
    // ws layout (bytes), base 138,889,536 (+27.2 MB Y2sep if ws allows):
    //   tcnt:     0          .. +1,024
    //   Bt1:      1,024      .. +278,528
    //   Bt2:      279,552    .. +34,816
    //   cur:      314,368    .. +200,704
    //   packed:   515,072    .. +12,845,056
    //   cnts:     13,360,128 .. +401,408
    //   seg:      13,761,536 .. +3,528,000
    //   embh/X1h: 17,289,536 .. +12,800,000
    //   Y1:       30,089,536 .. +108,800,000
    //   Y2sep:    138,889,536 .. +27,200,000  (fused path only)
    int*      tcnt   = (int*)(ws + 0);
    f16*      Bt1    = (f16*)(ws + 1024);
    f16*      Bt2    = (f16*)(ws + 279552);
    int*      cur    = (int*)(ws + 314368);
    unsigned* packed = (unsigned*)(ws + 515072);
    unsigned long long* cnts = (unsigned long long*)(ws + 13360128);
    unsigned* seg    = (unsigned*)(ws + 13761536);
    f16*      embh   = (f16*)(ws + 17289536);
    f16*      X1h    = (f16*)(ws + 17289536);    // fallback: aliases embh
    f16*      Y1     = (f16*)(ws + 30089536);
    f16*      Y2al   = (f16*)(ws + 30089536);    // fallback: aliases Y1
    f16*      Y2sep  = (f16*)(ws + 138889536);

    bool fuse = ws_size >= 138889536ull + 27200000ull;
    f16* Y2 = fuse ? Y2sep : Y2al;

    hipMemsetAsync(tcnt, 0, 1024, stream);

    // pre1: binA(98, first) | cast(6250) | build_B(613)
    k_pre1<<<NBA + CAST_BLK + BB_BLK, 256, 0, stream>>>(
        emb, W1, root1, W2, root2, ei, et, embh, Bt1, Bt2, tcnt, seg);

    // main: binB(196, first) | pad(28) | f16-A swizzled gemm1(3519)
    k_main<<<PAD + NWG1, 512, 0, stream>>>(embh, Bt1, Y1, tcnt, seg, cur, packed, cnts);

    if (fuse) {
        k_fuse<<<FBLK, 512, 0, stream>>>(cur, packed, cnts, Y1, b1, Bt2, Y2);
    } else {
        k_agg1f<<<(N_NODES * 64 + 255) / 256, 256, 0, stream>>>(cur, packed, cnts, Y1, b1, X1h);
        dim3 g2((J2 + 127) / 128, (N_NODES + 127) / 128);   // 3 x 391
        k_mfma<HID, f16><<<g2, 512, 0, stream>>>(X1h, Bt2, Y2, N_NODES, J2);
    }

    k_agg2f<<<(N_NODES * 64 + 255) / 256, 256, 0, stream>>>(cur, packed, cnts, Y2, b2, out);
}

// Round 19
// 134.427 us; speedup vs baseline: 1.0455x; 1.0455x over previous
//
#include <hip/hip_runtime.h>
#include <hip/hip_fp16.h>

#define N_NODES 50000
#define EMB 128
#define HID 64
#define NR 16
#define NC 16
#define NE 800000
#define J1 (NR*HID + HID)   /* 1088 = 17*64 */
#define J2 (NR*NC + NC)     /* 272  = 17*16 */
#define CAP 64              /* bucket capacity per dst */
#define NTILE 196           /* dst tiles of 256 nodes (50176 padded) */
#define SEGCAP 4500         /* edges per tile segment */
#define EPB 8192            /* edges per binA block */
#define NBA 98              /* binA blocks */
#define CAST_BLK 6250
#define BB_BLK 613
#define PAD 224             /* binB range padded to 8-aligned start for swizzle */
#define NWG1 3519           /* gemm blocks: 391 row x 9 col */

typedef _Float16 f16;
typedef __attribute__((ext_vector_type(8))) _Float16 f16x8;
typedef __attribute__((ext_vector_type(4))) _Float16 f16x4;
typedef __attribute__((ext_vector_type(4))) float f32x4;

// ---- pre-pass 1: [binA (98) | cast emb->f16 (6250) | build Bt1/Bt2 (613)] --
__global__ __launch_bounds__(256)
void k_pre1(const float* __restrict__ emb, const float* __restrict__ W1,
            const float* __restrict__ root1, const float* __restrict__ W2,
            const float* __restrict__ root2, const int* __restrict__ ei,
            const int* __restrict__ et, f16* __restrict__ embh,
            f16* __restrict__ Bt1, f16* __restrict__ Bt2,
            int* __restrict__ tcnt, unsigned* __restrict__ seg) {
    __shared__ unsigned rec[EPB];           // 32 KB
    __shared__ unsigned char tl[EPB];       // 8 KB
    __shared__ int hist[256], gbase[256];
    int bx = blockIdx.x, tid = threadIdx.x;
    if (bx < NBA) {                         // ---- binA ----
        hist[tid] = 0;
        __syncthreads();
        int e0 = bx * EPB;
#pragma unroll
        for (int k = 0; k < EPB / 256; k++) {
            int i = k * 256 + tid, e = e0 + i;
            unsigned t255 = 255, r = 0;
            if (e < NE) {
                int s = ei[e], d = ei[NE + e], t = et[e];
                t255 = (unsigned)(d >> 8);
                r = (unsigned)s | ((unsigned)t << 16) | ((unsigned)(d & 255) << 20);
                atomicAdd(&hist[t255], 1);
            }
            rec[i] = r; tl[i] = (unsigned char)t255;
        }
        __syncthreads();
        gbase[tid] = (hist[tid] > 0) ? atomicAdd(&tcnt[tid], hist[tid]) : 0;
        hist[tid] = 0;                      // reuse as local cursor
        __syncthreads();
#pragma unroll
        for (int k = 0; k < EPB / 256; k++) {
            int i = k * 256 + tid;
            unsigned char t = tl[i];
            if (t != 255) {
                int pos = atomicAdd(&hist[t], 1) + gbase[t];
                if (pos < SEGCAP) seg[(size_t)t * SEGCAP + pos] = rec[i];
            }
        }
    } else if (bx < NBA + CAST_BLK) {       // ---- cast ----
        int i = (bx - NBA) * 256 + tid;
        if (i < N_NODES * EMB / 4) {
            float4 v = reinterpret_cast<const float4*>(emb)[i];
            f16x4 r = {(f16)v.x, (f16)v.y, (f16)v.z, (f16)v.w};
            reinterpret_cast<f16x4*>(embh)[i] = r;
        }
    } else {                                // ---- build B ----
        int idx = (bx - NBA - CAST_BLK) * 256 + tid;
        const int total1 = J1 * EMB;   // 139264
        const int total2 = J2 * HID;   // 17408
        if (idx < total1) {
            int j = idx / EMB, i = idx % EMB;
            float v = (j < NR*HID) ? W1[((size_t)(j >> 6) * EMB + i) * HID + (j & 63)]
                                   : root1[i * HID + (j - NR*HID)];
            Bt1[idx] = (f16)v;
        } else if (idx < total1 + total2) {
            int t = idx - total1;
            int j = t / HID, i = t % HID;
            float v = (j < NR*NC) ? W2[((size_t)(j >> 4) * HID + i) * NC + (j & 15)]
                                  : root2[i * NC + (j - NR*NC)];
            Bt2[t] = (f16)v;
        }
    }
}

// ---- main: [binB (196) | GEMM1 f16-A, bijective XCD swizzle (3519)] --------
__global__ __launch_bounds__(512)
void k_main(const f16* __restrict__ A, const f16* __restrict__ Bt,
            f16* __restrict__ C, const int* __restrict__ tcnt,
            const unsigned* __restrict__ seg, int* __restrict__ cur,
            unsigned* __restrict__ packed, unsigned long long* __restrict__ cnts) {
    constexpr int K = EMB, KP = K + 8;
    __shared__ __align__(16) char smem[128 * KP * 2 * 2];   // 69,632 B union
    int wg = blockIdx.x, tid = threadIdx.x;

    if (wg < NTILE) {                       // ================ binB ========
        int* bcnt = (int*)smem;                        // 1 KB
        unsigned* bkt = (unsigned*)(smem + 1024);      // 64 KB
        for (int i = tid; i < 256; i += 512) bcnt[i] = 0;
        __syncthreads();
        int m = tcnt[wg]; if (m > SEGCAP) m = SEGCAP;
        for (int i = tid; i < m; i += 512) {
            unsigned r = seg[(size_t)wg * SEGCAP + i];
            int dl = (r >> 20) & 255;
            int pos = atomicAdd(&bcnt[dl], 1);
            if (pos < CAP) bkt[dl * CAP + pos] = (r & 0xFFFFu) * 17u + ((r >> 16) & 15u);
        }
        __syncthreads();
        const uint4* s4 = (const uint4*)bkt;
        uint4* d4 = (uint4*)(packed + (size_t)wg * 256 * CAP);
        for (int i = tid; i < 256 * CAP / 4; i += 512) d4[i] = s4[i];
        if (tid < 256) {
            int deg = bcnt[tid]; if (deg > CAP) deg = CAP;
            unsigned long long cc = 0;
            for (int i = 0; i < deg; i++) {
                unsigned t = bkt[tid * CAP + i] % 17u;   // 0..15 for stored entries
                cc += 1ull << (4 * t);
            }
            cnts[wg * 256 + tid] = cc;
            cur[wg * 256 + tid] = bcnt[tid];
        }
        return;
    }
    if (wg < PAD) return;                   // 28 idle pad blocks
    // ================ gemm path ================
    f16* As = (f16*)smem;
    f16* Bs = As + 128 * KP;
    int g = wg - PAD;                       // PAD%8==0 -> g&7 == real XCD
    constexpr int qq = NWG1 / 8, rm = NWG1 % 8;    // 439, 7
    int x = g & 7, slot = g >> 3;
    int vg = (x < rm) ? x * (qq + 1) + slot
                      : rm * (qq + 1) + (x - rm) * qq + slot;
    int m0 = (vg / 9) * 128, n0 = (vg % 9) * 128;

    constexpr int V = K / 8;
    for (int idx = tid; idx < 128 * V; idx += 512) {
        int rr = idx / V, c = idx % V;
        f16x8 va = {}, vb = {};
        if (m0 + rr < N_NODES) va = *reinterpret_cast<const f16x8*>(A + (size_t)(m0 + rr) * K + c * 8);
        if (n0 + rr < J1)      vb = *reinterpret_cast<const f16x8*>(Bt + (size_t)(n0 + rr) * K + c * 8);
        *reinterpret_cast<f16x8*>(&As[rr * KP + c * 8]) = va;
        *reinterpret_cast<f16x8*>(&Bs[rr * KP + c * 8]) = vb;
    }
    __syncthreads();

    int w = tid >> 6, lane = tid & 63;
    int wr = (w >> 2) * 64, wc = (w & 3) * 32;
    int lr = lane & 15, lk = (lane >> 4) * 8;

    f32x4 acc[4][2];
#pragma unroll
    for (int mm = 0; mm < 4; mm++)
#pragma unroll
        for (int nn = 0; nn < 2; nn++) acc[mm][nn] = (f32x4){0.f, 0.f, 0.f, 0.f};

#pragma unroll
    for (int k0 = 0; k0 < K; k0 += 32) {
        f16x8 a[4], b[2];
#pragma unroll
        for (int mm = 0; mm < 4; mm++)
            a[mm] = *reinterpret_cast<const f16x8*>(&As[(wr + mm*16 + lr) * KP + k0 + lk]);
#pragma unroll
        for (int nn = 0; nn < 2; nn++)
            b[nn] = *reinterpret_cast<const f16x8*>(&Bs[(wc + nn*16 + lr) * KP + k0 + lk]);
#pragma unroll
        for (int mm = 0; mm < 4; mm++)
#pragma unroll
            for (int nn = 0; nn < 2; nn++)
                acc[mm][nn] = __builtin_amdgcn_mfma_f32_16x16x32_f16(a[mm], b[nn], acc[mm][nn], 0, 0, 0);
    }

    // ---- epilogue: LDS transpose (alias As/Bs) -> vectorized f16x8 stores --
    __syncthreads();                        // all frag reads drained
    f16* Cs = (f16*)smem;                   // 128 x 136 f16 = 34,816 B
    int gq = lane >> 4;
#pragma unroll
    for (int mm = 0; mm < 4; mm++)
#pragma unroll
        for (int nn = 0; nn < 2; nn++)
#pragma unroll
            for (int q = 0; q < 4; q++)
                Cs[(wr + mm*16 + gq*4 + q) * 136 + wc + nn*16 + lr] = (f16)acc[mm][nn][q];
    __syncthreads();
#pragma unroll
    for (int it = 0; it < 4; it++) {
        int idx = it * 512 + tid;
        int row = idx >> 4, cg = idx & 15;
        int grow = m0 + row, gcol = n0 + cg * 8;
        if (grow < N_NODES && gcol < J1)
            *reinterpret_cast<f16x8*>(C + (size_t)grow * J1 + gcol) =
                *reinterpret_cast<const f16x8*>(&Cs[row * 136 + cg * 8]);
    }
}

// ---- MFMA GEMM for layer 2 (transpose epilogue) -----------------------------
template<int K, typename OutT>
__global__ __launch_bounds__(512)
void k_mfma(const f16* __restrict__ A, const f16* __restrict__ Bt,
            OutT* __restrict__ C, int N, int J) {
    constexpr int KP = K + 8;
    constexpr int SM = (2 * 128 * KP * 2 > 128 * 136 * 2) ? 2 * 128 * KP * 2
                                                          : 128 * 136 * 2;
    __shared__ __align__(16) char smem[SM];
    f16* As = (f16*)smem;
    f16* Bs = As + 128 * KP;
    int tid = threadIdx.x;
    int m0 = blockIdx.y * 128, n0 = blockIdx.x * 128;

    constexpr int V = K / 8;
    for (int idx = tid; idx < 128 * V; idx += 512) {
        int r = idx / V, c = idx % V;
        f16x8 va = {}, vb = {};
        if (m0 + r < N) va = *reinterpret_cast<const f16x8*>(A + (size_t)(m0 + r) * K + c * 8);
        if (n0 + r < J) vb = *reinterpret_cast<const f16x8*>(Bt + (size_t)(n0 + r) * K + c * 8);
        *reinterpret_cast<f16x8*>(&As[r * KP + c * 8]) = va;
        *reinterpret_cast<f16x8*>(&Bs[r * KP + c * 8]) = vb;
    }
    __syncthreads();

    int w = tid >> 6, lane = tid & 63;
    int wr = (w >> 2) * 64, wc = (w & 3) * 32;
    int lr = lane & 15, lk = (lane >> 4) * 8;

    f32x4 acc[4][2];
#pragma unroll
    for (int mm = 0; mm < 4; mm++)
#pragma unroll
        for (int nn = 0; nn < 2; nn++) acc[mm][nn] = (f32x4){0.f, 0.f, 0.f, 0.f};

#pragma unroll
    for (int k0 = 0; k0 < K; k0 += 32) {
        f16x8 a[4], b[2];
#pragma unroll
        for (int mm = 0; mm < 4; mm++)
            a[mm] = *reinterpret_cast<const f16x8*>(&As[(wr + mm*16 + lr) * KP + k0 + lk]);
#pragma unroll
        for (int nn = 0; nn < 2; nn++)
            b[nn] = *reinterpret_cast<const f16x8*>(&Bs[(wc + nn*16 + lr) * KP + k0 + lk]);
#pragma unroll
        for (int mm = 0; mm < 4; mm++)
#pragma unroll
            for (int nn = 0; nn < 2; nn++)
                acc[mm][nn] = __builtin_amdgcn_mfma_f32_16x16x32_f16(a[mm], b[nn], acc[mm][nn], 0, 0, 0);
    }

    __syncthreads();
    f16* Cs = (f16*)smem;                   // 128 x 136 f16
    int gq = lane >> 4;
#pragma unroll
    for (int mm = 0; mm < 4; mm++)
#pragma unroll
        for (int nn = 0; nn < 2; nn++)
#pragma unroll
            for (int q = 0; q < 4; q++)
                Cs[(wr + mm*16 + gq*4 + q) * 136 + wc + nn*16 + lr] = (f16)acc[mm][nn][q];
    __syncthreads();
#pragma unroll
    for (int it = 0; it < 4; it++) {
        int idx = it * 512 + tid;
        int row = idx >> 4, cg = idx & 15;
        int grow = m0 + row, gcol = n0 + cg * 8;
        if (grow < N && gcol < J) {
            f16x8 v = *reinterpret_cast<const f16x8*>(&Cs[row * 136 + cg * 8]);
            if constexpr (sizeof(OutT) == 2) {
                *reinterpret_cast<f16x8*>((f16*)C + (size_t)grow * J + gcol) = v;
            } else {
#pragma unroll
                for (int j = 0; j < 8; j++)
                    C[(size_t)grow * J + gcol + j] = (OutT)v[j];
            }
        }
    }
}

// ---- fused layer-1 aggregation + finalize ----------------------------------
// wave/node; 2x4 edge-groups in flight (8 gathers issued before consume).
__global__ __launch_bounds__(256)
void k_agg1f(const int* __restrict__ cur, const unsigned* __restrict__ packed,
             const unsigned long long* __restrict__ cnts,
             const f16* __restrict__ Y1, const float* __restrict__ b1,
             f16* __restrict__ X1h) {
    int n = (blockIdx.x * 256 + threadIdx.x) >> 6;
    if (n >= N_NODES) return;
    int lane = threadIdx.x & 63;
    int deg = cur[n]; if (deg > CAP) deg = CAP;
    unsigned long long cc = cnts[n];
    unsigned my = packed[(size_t)n * CAP + lane];   // stale for lane>=deg, masked
    unsigned tp = (my % 17u) & 15u;
    int myc = (int)((cc >> (4 * tp)) & 15ull);
    float w_my = 1.0f / fmaxf((float)myc, 1.0f);
    int c4 = lane & 15, grp = lane >> 4;
    const f16* Yb = Y1 + c4 * 4;
    float a0 = 0.f, a1 = 0.f, a2 = 0.f, a3 = 0.f;
    for (int i = 0; i < deg; i += 8) {              // wave-uniform bound
        int idx0 = i + grp;                         // <= 59
        int idx1 = i + 4 + grp;                     // <= 63
        unsigned e0 = __shfl(my, idx0), e1 = __shfl(my, idx1);
        float w0 = __shfl(w_my, idx0), w1 = __shfl(w_my, idx1);
        bool p0 = idx0 < deg, p1 = idx1 < deg;
        f16x4 v0 = {}, v1 = {};
        if (p0) v0 = *reinterpret_cast<const f16x4*>(Yb + ((size_t)e0 << 6));
        if (p1) v1 = *reinterpret_cast<const f16x4*>(Yb + ((size_t)e1 << 6));
        if (p0) { a0 += w0 * (float)v0[0]; a1 += w0 * (float)v0[1];
                  a2 += w0 * (float)v0[2]; a3 += w0 * (float)v0[3]; }
        if (p1) { a0 += w1 * (float)v1[0]; a1 += w1 * (float)v1[1];
                  a2 += w1 * (float)v1[2]; a3 += w1 * (float)v1[3]; }
    }
    a0 += __shfl_xor(a0, 16); a0 += __shfl_xor(a0, 32);
    a1 += __shfl_xor(a1, 16); a1 += __shfl_xor(a1, 32);
    a2 += __shfl_xor(a2, 16); a2 += __shfl_xor(a2, 32);
    a3 += __shfl_xor(a3, 16); a3 += __shfl_xor(a3, 32);
    if (grp == 0) {
        f16x4 rt = *reinterpret_cast<const f16x4*>(Y1 + ((size_t)n * 17 + 16) * 64 + c4 * 4);
        float4 bb = *reinterpret_cast<const float4*>(b1 + c4 * 4);
        f16x4 o = {(f16)fmaxf(a0 + (float)rt[0] + bb.x, 0.f),
                   (f16)fmaxf(a1 + (float)rt[1] + bb.y, 0.f),
                   (f16)fmaxf(a2 + (float)rt[2] + bb.z, 0.f),
                   (f16)fmaxf(a3 + (float)rt[3] + bb.w, 0.f)};
        *reinterpret_cast<f16x4*>(X1h + (size_t)n * HID + c4 * 4) = o;
    }
}

// ---- fused layer-2 aggregation + finalize ----------------------------------
// wave/node; 2x16 edge-groups in flight (f16x4 loads, Y2 f16).
__global__ __launch_bounds__(256)
void k_agg2f(const int* __restrict__ cur, const unsigned* __restrict__ packed,
             const unsigned long long* __restrict__ cnts,
             const f16* __restrict__ Y2, const float* __restrict__ b2,
             float* __restrict__ out) {
    int n = (blockIdx.x * 256 + threadIdx.x) >> 6;
    if (n >= N_NODES) return;
    int lane = threadIdx.x & 63;
    int deg = cur[n]; if (deg > CAP) deg = CAP;
    unsigned long long cc = cnts[n];
    unsigned my = packed[(size_t)n * CAP + lane];
    unsigned tp = (my % 17u) & 15u;
    int myc = (int)((cc >> (4 * tp)) & 15ull);
    float w_my = 1.0f / fmaxf((float)myc, 1.0f);
    int c4 = lane & 3, grp = lane >> 2;             // 16 groups x 4 quads
    const f16* Yb = Y2 + c4 * 4;
    float a0 = 0.f, a1 = 0.f, a2 = 0.f, a3 = 0.f;
    for (int i = 0; i < deg; i += 32) {             // wave-uniform bound
        int idx0 = i + grp;                         // <= 47
        int idx1 = i + 16 + grp;                    // <= 63
        unsigned e0 = __shfl(my, idx0), e1 = __shfl(my, idx1);
        float w0 = __shfl(w_my, idx0), w1 = __shfl(w_my, idx1);
        bool p0 = idx0 < deg, p1 = idx1 < deg;
        f16x4 v0 = {}, v1 = {};
        if (p0) v0 = *reinterpret_cast<const f16x4*>(Yb + ((size_t)e0 << 4));
        if (p1) v1 = *reinterpret_cast<const f16x4*>(Yb + ((size_t)e1 << 4));
        if (p0) { a0 += w0 * (float)v0[0]; a1 += w0 * (float)v0[1];
                  a2 += w0 * (float)v0[2]; a3 += w0 * (float)v0[3]; }
        if (p1) { a0 += w1 * (float)v1[0]; a1 += w1 * (float)v1[1];
                  a2 += w1 * (float)v1[2]; a3 += w1 * (float)v1[3]; }
    }
#pragma unroll
    for (int sh = 4; sh <= 32; sh <<= 1) {
        a0 += __shfl_xor(a0, sh); a1 += __shfl_xor(a1, sh);
        a2 += __shfl_xor(a2, sh); a3 += __shfl_xor(a3, sh);
    }
    if (grp == 0) {                                 // lanes 0..3
        f16x4 rt = *reinterpret_cast<const f16x4*>(Y2 + (((size_t)n * 17 + 16) << 4) + c4 * 4);
        float4 bb = *reinterpret_cast<const float4*>(b2 + c4 * 4);
        float4 o;
        o.x = 1.0f / (1.0f + expf(-(a0 + (float)rt[0] + bb.x)));
        o.y = 1.0f / (1.0f + expf(-(a1 + (float)rt[1] + bb.y)));
        o.z = 1.0f / (1.0f + expf(-(a2 + (float)rt[2] + bb.z)));
        o.w = 1.0f / (1.0f + expf(-(a3 + (float)rt[3] + bb.w)));
        *reinterpret_cast<float4*>(out + (size_t)n * NC + c4 * 4) = o;
    }
}

extern "C" void kernel_launch(void* const* d_in, const int* in_sizes, int n_in,
                              void* d_out, int out_size, void* d_ws, size_t ws_size,
                              hipStream_t stream) {
    const float* emb   = (const float*)d_in[0];
    const float* W1    = (const float*)d_in[1];
    const float* root1 = (const float*)d_in[2];
    const float* b1    = (const float*)d_in[3];
    const float* W2    = (const float*)d_in[4];
    const float* root2 = (const float*)d_in[5];
    const float* b2    = (const float*)d_in[6];
    const int*   ei    = (const int*)d_in[7];    // [2, NE]: src then dst
    const int*   et    = (const int*)d_in[8];
    float* out = (float*)d_out;

    char* ws = (char*)d_ws;
    // ws layout (bytes), total 138,889,536 (r15/r17 layout):
    //   tcnt:     0          .. +1,024        (196 i32, padded)
    //   Bt1:      1,024      .. +278,528      (1088x128 f16)
    //   Bt2:      279,552    .. +34,816       (272x64 f16)
    //   cur:      314,368    .. +200,704      (50176 i32)
    //   packed:   515,072    .. +12,845,056   (50176x64 u32)
    //   cnts:     13,360,128 .. +401,408      (50176 u64 nibble type-counts)
    //   seg:      13,761,536 .. +3,528,000    (196x4500 u32)
    //   embh/X1h: 17,289,536 .. +12,800,000   (embh dies at k_main; X1h aliases)
    //   Y1/Y2:    30,089,536 .. +108,800,000  (Y1 f16; Y2 f16 aliased, dead Y1)
    int*      tcnt   = (int*)(ws + 0);
    f16*      Bt1    = (f16*)(ws + 1024);
    f16*      Bt2    = (f16*)(ws + 279552);
    int*      cur    = (int*)(ws + 314368);
    unsigned* packed = (unsigned*)(ws + 515072);
    unsigned long long* cnts = (unsigned long long*)(ws + 13360128);
    unsigned* seg    = (unsigned*)(ws + 13761536);
    f16*      embh   = (f16*)(ws + 17289536);
    f16*      X1h    = (f16*)(ws + 17289536);    // aliases embh (disjoint lifetime)
    f16*      Y1     = (f16*)(ws + 30089536);
    f16*      Y2     = (f16*)(ws + 30089536);    // aliases Y1 (dead after agg1f)

    hipMemsetAsync(tcnt, 0, 1024, stream);

    // pre1: binA(98, first) | cast(6250) | build_B(613)
    k_pre1<<<NBA + CAST_BLK + BB_BLK, 256, 0, stream>>>(
        emb, W1, root1, W2, root2, ei, et, embh, Bt1, Bt2, tcnt, seg);

    // main: binB(196, first) | pad(28) | f16-A swizzled gemm1(3519)
    k_main<<<PAD + NWG1, 512, 0, stream>>>(embh, Bt1, Y1, tcnt, seg, cur, packed, cnts);

    k_agg1f<<<(N_NODES * 64 + 255) / 256, 256, 0, stream>>>(cur, packed, cnts, Y1, b1, X1h);

    dim3 g2((J2 + 127) / 128, (N_NODES + 127) / 128);   // 3 x 391
    k_mfma<HID, f16><<<g2, 512, 0, stream>>>(X1h, Bt2, Y2, N_NODES, J2);

    k_agg2f<<<(N_NODES * 64 + 255) / 256, 256, 0, stream>>>(cur, packed, cnts, Y2, b2, out);
}